// Round 6
// baseline (871.438 us; speedup 1.0000x reference)
//
#include <hip/hip_runtime.h>
#include <math.h>

#define NBANDS 31
#define FT 257000

typedef __attribute__((ext_vector_type(8))) short bh8;
typedef __attribute__((ext_vector_type(4))) float f4;

__constant__ int d_bs[NBANDS] = {0,1,1,2,2,2,3,3,4,5,6,7,8,10,11,13,16,19,23,27,32,38,45,54,64,76,91,108,128,152,181};
__constant__ int d_be[NBANDS] = {2,3,3,3,4,4,5,6,7,8,9,11,12,14,17,20,24,28,33,39,46,55,65,77,92,109,129,153,182,216,257};

__device__ __forceinline__ unsigned short b16u(float v) {
  __bf16 h = (__bf16)v;
  return __builtin_bit_cast(unsigned short, h);
}
__device__ __forceinline__ unsigned pk2(float a, float b) {
  return (unsigned)b16u(a) | ((unsigned)b16u(b) << 16);
}
__device__ __forceinline__ float hann1(int i, int L) {
  return 0.5f - 0.5f * cosf(6.283185307179586f * (float)i / (float)L);
}

// ---- weight f32 -> bf16 prep, permuted into MFMA-fragment order ----
__global__ __launch_bounds__(256) void prep_w(
    const float* __restrict__ enc_w, const float* __restrict__ dec_w,
    const float* __restrict__ qw, const float* __restrict__ kw,
    const float* __restrict__ vw, const float* __restrict__ ow,
    unsigned short* __restrict__ w16) {
  const int stride = gridDim.x * blockDim.x;
  for (int i = blockIdx.x * blockDim.x + threadIdx.x; i < 513024; i += stride) {
    float v;
    if (i < 190464) {                      // enc: K=64, KT=2
      const int k = i / 6144, r = i - k * 6144;
      const int tile = r >> 9, li = r & 511;
      const int lane = li >> 3, j = li & 7;
      const int g = lane >> 4, n = lane & 15;
      const int mt = tile >> 1, kt = tile & 1;
      v = enc_w[k * 6144 + (mt * 16 + n) * 64 + kt * 32 + g * 8 + j];
    } else if (i < 476160) {               // dec: K=96, KT=3
      const int i2 = i - 190464;
      const int k = i2 / 9216, r = i2 - k * 9216;
      const int tile = r >> 9, li = r & 511;
      const int lane = li >> 3, j = li & 7;
      const int g = lane >> 4, n = lane & 15;
      const int mt = tile / 3, kt = tile - mt * 3;
      v = dec_w[k * 9216 + (mt * 16 + n) * 96 + kt * 32 + g * 8 + j];
    } else {                               // q,k,v,o
      const int i2 = i - 476160;
      const int a = i2 / 9216, r = i2 - a * 9216;
      const int tile = r >> 9, li = r & 511;
      const int lane = li >> 3, j = li & 7;
      const int g = lane >> 4, n = lane & 15;
      const int mt = tile / 3, kt = tile - mt * 3;
      const float* src = (a == 0) ? qw : (a == 1) ? kw : (a == 2) ? vw : ow;
      v = src[(mt * 16 + n) * 96 + kt * 32 + g * 8 + j];
    }
    w16[i] = b16u(v);
  }
}

__global__ __launch_bounds__(192) void qp_kernel(const float* __restrict__ doa,
                                                 const float* __restrict__ dqg_w,
                                                 const float* __restrict__ dqg_b,
                                                 float* __restrict__ gbuf) {
  const int k = blockIdx.x, b = blockIdx.y;
  const int tid = threadIdx.x;
  __shared__ float sdoa[36];
  if (tid < 36) sdoa[tid] = doa[b * 36 + tid];
  __syncthreads();
  const float* wr = dqg_w + (k * 192 + tid) * 36;
  float acc = dqg_b[k * 192 + tid];
  #pragma unroll
  for (int i = 0; i < 36; ++i) acc = fmaf(wr[i], sdoa[i], acc);
  if (tid < 96) acc += 1.0f;
  gbuf[(k * 4 + b) * 192 + tid] = acc;
}

#define LDSWAIT asm volatile("s_waitcnt lgkmcnt(0)" ::: "memory")

__device__ __forceinline__ void load6(bh8* dst, const unsigned short* p, int tstep) {
  #pragma unroll
  for (int mt = 0; mt < 6; ++mt)
    dst[mt] = *reinterpret_cast<const bh8*>(p + ((mt * tstep) << 9));
}
__device__ __forceinline__ void mfma6(f4* acc, const bh8* wf, bh8 bop) {
  #pragma unroll
  for (int mt = 0; mt < 6; ++mt)
    acc[mt] = __builtin_amdgcn_mfma_f32_16x16x32_bf16(wf[mt], bop, acc[mt], 0, 0, 0);
}
__device__ __forceinline__ void init6(f4* acc, const float* s, int off) {
  #pragma unroll
  for (int mt = 0; mt < 6; ++mt) {
    const float4 bb = *reinterpret_cast<const float4*>(s + mt * 16 + off);
    acc[mt] = (f4){bb.x, bb.y, bb.z, bb.w};
  }
}
__device__ __forceinline__ void ln96(const f4* acc, float& mean, float& rs) {
  float sm = 0.f, sq = 0.f;
  #pragma unroll
  for (int mt = 0; mt < 6; ++mt)
    #pragma unroll
    for (int r = 0; r < 4; ++r) { const float v = acc[mt][r]; sm += v; sq = fmaf(v, v, sq); }
  sm += __shfl_xor(sm, 16); sm += __shfl_xor(sm, 32);
  sq += __shfl_xor(sq, 16); sq += __shfl_xor(sq, 32);
  mean = sm * (1.f / 96.f);
  rs = rsqrtf(sq * (1.f / 96.f) - mean * mean + 1e-5f);
}

// ---- fully fused MFMA kernel; group-pipelined weight loads; LDS-staged biases ----
__global__ __launch_bounds__(256, 4) void fused_mfma(
    const float* __restrict__ mix, const float* __restrict__ spin,
    const unsigned short* __restrict__ enc16, const float* __restrict__ enc_b, const float* __restrict__ enc_a,
    const unsigned short* __restrict__ dec16, const float* __restrict__ dec_b, const float* __restrict__ dec_a,
    const float* __restrict__ gb,
    const unsigned short* __restrict__ q16, const float* __restrict__ qb,
    const unsigned short* __restrict__ k16, const float* __restrict__ kb,
    const unsigned short* __restrict__ v16, const float* __restrict__ vb,
    const unsigned short* __restrict__ o16, const float* __restrict__ ob,
    float* __restrict__ out) {
  const int id0 = (int)blockIdx.x;
  const int id  = (id0 & 7) * 2056 + (id0 >> 3);   // bijective XCD swizzle
  const int tt  = id & 15;
  const int fb  = id >> 4;
  const int f   = fb % 257;
  const int b   = fb / 257;
  const int t0  = tt << 6;

  const int tid  = threadIdx.x;
  const int lane = tid & 63;
  const int w    = tid >> 6;
  const int g    = lane >> 4;
  const int n    = lane & 15;
  const int col  = (w << 4) + n;
  const int t    = t0 + col;
  const bool tv  = t < 1000;
  const int tcl  = tv ? t : 999;
  const int sw   = (n & 7) << 3;
  const int lb   = lane << 3;

  __shared__ __align__(16) unsigned short XT[64 * 128];
  __shared__ __align__(16) float stage[2304];   // [nb][encB 96|decB 96|gb 192] + [qb|kb|vb|ob]
  unsigned short* xw = XT + col * 128;

  // band range covering f is contiguous
  int k0 = 0; while (d_be[k0] <= f) ++k0;
  int k1 = k0; while (k1 < NBANDS && d_bs[k1] <= f) ++k1;
  const int nb = k1 - k0;

  // ---- cooperative stage of biases + FiLM params ----
  {
    const int tot = nb * 384 + 384;
    for (int i = tid; i < tot; i += 256) {
      const int kk = i / 384, r = i - kk * 384;
      float v;
      if (kk < nb) {
        v = (r < 96) ? enc_b[(k0 + kk) * 96 + r]
          : (r < 192) ? dec_b[(k0 + kk) * 96 + (r - 96)]
          : gb[((k0 + kk) * 4 + b) * 192 + (r - 192)];
      } else {
        v = (r < 96) ? qb[r] : (r < 192) ? kb[r - 96] : (r < 288) ? vb[r - 192] : ob[r - 288];
      }
      stage[i] = v;
    }
  }

  float wsum = 0.f;
  for (int k = k0; k < k1; ++k) wsum += hann1(f - d_bs[k], d_be[k] - d_bs[k]);
  const float winv = 1.0f / fmaxf(wsum, 1e-8f);

  const float* spL = spin + b * 64 * FT + f * 1000 + tcl;
  const float* mxL = mix  + b * 96 * FT + f * 1000 + tcl;

  // spin prefetch (read-once)
  bh8 spb[2];
  {
    float spf[16];
    #pragma unroll
    for (int j = 0; j < 8; ++j) spf[j]     = __builtin_nontemporal_load(spL + (g * 8 + j) * FT);
    #pragma unroll
    for (int j = 0; j < 8; ++j) spf[8 + j] = __builtin_nontemporal_load(spL + (32 + g * 8 + j) * FT);
    #pragma unroll
    for (int kt = 0; kt < 2; ++kt)
      #pragma unroll
      for (int j = 0; j < 8; ++j) spb[kt][j] = (short)b16u(spf[kt * 8 + j]);
  }

  __syncthreads();   // stage visible

  f4 macc[6];
  #pragma unroll
  for (int mt = 0; mt < 6; ++mt) macc[mt] = (f4){0.f, 0.f, 0.f, 0.f};

  bh8 wA[6], wB[6];
  load6(wA, enc16 + k0 * 6144 + lb, 2);          // enc g0 of first band

  const int oo = g * 4;                          // float offset within 96-row vector

  // ---------------- band loop: INV: wA holds enc g0(k) at entry ----------------
  for (int k = k0; k < k1; ++k) {
    const unsigned short* ew  = enc16 + k * 6144 + lb;
    const unsigned short* dwp = dec16 + k * 9216 + lb;
    const float* stg = stage + (k - k0) * 384;

    load6(wB, ew + 512, 2);                      // enc g1
    f4 acc[6];
    init6(acc, stg, oo);                         // enc bias from LDS
    mfma6(acc, wA, spb[0]);
    load6(wA, dwp, 3);                           // dec g0
    mfma6(acc, wB, spb[1]);
    load6(wB, dwp + 512, 3);                     // dec g1

    float mean, rs;
    ln96(acc, mean, rs);
    const float ea = enc_a[k];
    #pragma unroll
    for (int mt = 0; mt < 6; ++mt) {
      const float4 ga = *reinterpret_cast<const float4*>(stg + 192 + mt * 16 + oo);
      const float4 be = *reinterpret_cast<const float4*>(stg + 288 + mt * 16 + oo);
      float x0 = (acc[mt][0] - mean) * rs; x0 = (x0 >= 0.f) ? x0 : ea * x0;
      float x1 = (acc[mt][1] - mean) * rs; x1 = (x1 >= 0.f) ? x1 : ea * x1;
      float x2 = (acc[mt][2] - mean) * rs; x2 = (x2 >= 0.f) ? x2 : ea * x2;
      float x3 = (acc[mt][3] - mean) * rs; x3 = (x3 >= 0.f) ? x3 : ea * x3;
      uint2 u;
      u.x = pk2(fmaf(ga.x, x0, be.x), fmaf(ga.y, x1, be.y));
      u.y = pk2(fmaf(ga.z, x2, be.z), fmaf(ga.w, x3, be.w));
      *reinterpret_cast<uint2*>(xw + ((mt * 16 + g * 4) ^ sw)) = u;
    }
    LDSWAIT;

    f4 dacc[6];
    init6(dacc, stg + 96, oo);                   // dec bias from LDS
    const bh8 bf0 = *reinterpret_cast<const bh8*>(xw + ((0 * 32 + g * 8) ^ sw));
    mfma6(dacc, wA, bf0);
    load6(wA, dwp + 1024, 3);                    // dec g2
    const bh8 bf1 = *reinterpret_cast<const bh8*>(xw + ((1 * 32 + g * 8) ^ sw));
    mfma6(dacc, wB, bf1);
    const bh8 bf2 = *reinterpret_cast<const bh8*>(xw + ((2 * 32 + g * 8) ^ sw));
    mfma6(dacc, wA, bf2);

    // prefetch next band's enc g0 (or Q g0) — overlaps LN2
    {
      const bool more = (k + 1 < k1);
      const unsigned short* nx = more ? (enc16 + (k + 1) * 6144 + lb) : (q16 + lb);
      load6(wA, nx, more ? 2 : 3);
    }

    float mean2, rs2;
    ln96(dacc, mean2, rs2);
    const float da = dec_a[k];
    const float win = hann1(f - d_bs[k], d_be[k] - d_bs[k]);
    #pragma unroll
    for (int mt = 0; mt < 6; ++mt)
      #pragma unroll
      for (int r = 0; r < 4; ++r) {
        float x = (dacc[mt][r] - mean2) * rs2;
        x = (x >= 0.f) ? x : da * x;
        macc[mt][r] = fmaf(win, x, macc[mt][r]);
      }
  }

  // ---- mix loads (cached; residual re-read hits L2) ----
  float mxf[24];
  #pragma unroll
  for (int kt = 0; kt < 3; ++kt)
    #pragma unroll
    for (int j = 0; j < 8; ++j) mxf[kt * 8 + j] = mxL[(kt * 32 + g * 8 + j) * FT];

  // ---- merged -> XT ----
  #pragma unroll
  for (int mt = 0; mt < 6; ++mt) {
    uint2 u;
    u.x = pk2(macc[mt][0] * winv, macc[mt][1] * winv);
    u.y = pk2(macc[mt][2] * winv, macc[mt][3] * winv);
    *reinterpret_cast<uint2*>(xw + ((mt * 16 + g * 4) ^ sw)) = u;
  }
  LDSWAIT;
  bh8 gfr[3];
  #pragma unroll
  for (int kt = 0; kt < 3; ++kt) gfr[kt] = *reinterpret_cast<const bh8*>(xw + ((kt * 32 + g * 8) ^ sw));

  bh8 mxb[3];
  #pragma unroll
  for (int kt = 0; kt < 3; ++kt)
    #pragma unroll
    for (int j = 0; j < 8; ++j) mxb[kt][j] = (short)b16u(mxf[kt * 8 + j]);

  const float* stQ = stage + nb * 384;

  // ---- Q/K/V/O pipelined chain (wA holds Q g0) ----
  f4 qacc[6];
  init6(qacc, stQ, oo);
  load6(wB, q16 + 512 + lb, 3);  mfma6(qacc, wA, mxb[0]);
  load6(wA, q16 + 1024 + lb, 3); mfma6(qacc, wB, mxb[1]);
  load6(wB, k16 + lb, 3);        mfma6(qacc, wA, mxb[2]);
  f4 kacc[6];
  init6(kacc, stQ + 96, oo);
  load6(wA, k16 + 512 + lb, 3);  mfma6(kacc, wB, gfr[0]);
  load6(wB, k16 + 1024 + lb, 3); mfma6(kacc, wA, gfr[1]);
  load6(wA, v16 + lb, 3);        mfma6(kacc, wB, gfr[2]);

  float p = 0.f;
  #pragma unroll
  for (int mt = 0; mt < 6; ++mt)
    #pragma unroll
    for (int r = 0; r < 4; ++r) p = fmaf(qacc[mt][r], kacc[mt][r], p);
  p += __shfl_xor(p, 16); p += __shfl_xor(p, 32);
  const float sig = 1.f / (1.f + __expf(-p * 0.10206207261596575f));

  f4 vacc[6];
  init6(vacc, stQ + 192, oo);
  load6(wB, v16 + 512 + lb, 3);  mfma6(vacc, wA, gfr[0]);
  load6(wA, v16 + 1024 + lb, 3); mfma6(vacc, wB, gfr[1]);
  load6(wB, o16 + lb, 3);        mfma6(vacc, wA, gfr[2]);

  #pragma unroll
  for (int mt = 0; mt < 6; ++mt) {
    uint2 u;
    u.x = pk2(vacc[mt][0] * sig, vacc[mt][1] * sig);
    u.y = pk2(vacc[mt][2] * sig, vacc[mt][3] * sig);
    *reinterpret_cast<uint2*>(xw + ((mt * 16 + g * 4) ^ sw)) = u;
  }
  // residual loads issue before the wait, consumed at store
  float mres[6][4];
  #pragma unroll
  for (int mt = 0; mt < 6; ++mt)
    #pragma unroll
    for (int r = 0; r < 4; ++r) mres[mt][r] = mxL[(mt * 16 + g * 4 + r) * FT];
  LDSWAIT;
  bh8 afr[3];
  #pragma unroll
  for (int kt = 0; kt < 3; ++kt) afr[kt] = *reinterpret_cast<const bh8*>(xw + ((kt * 32 + g * 8) ^ sw));

  f4 oacc[6];
  init6(oacc, stQ + 288, oo);
  load6(wA, o16 + 512 + lb, 3);  mfma6(oacc, wB, afr[0]);
  load6(wB, o16 + 1024 + lb, 3); mfma6(oacc, wA, afr[1]);
  mfma6(oacc, wB, afr[2]);

  if (tv) {
    #pragma unroll
    for (int mt = 0; mt < 6; ++mt) {
      const int base = (b * 96 + mt * 16 + g * 4) * FT + f * 1000 + t;
      #pragma unroll
      for (int r = 0; r < 4; ++r)
        __builtin_nontemporal_store(mres[mt][r] + oacc[mt][r], out + base + r * FT);
    }
  }
}

extern "C" void kernel_launch(void* const* d_in, const int* in_sizes, int n_in,
                              void* d_out, int out_size, void* d_ws, size_t ws_size,
                              hipStream_t stream) {
  (void)in_sizes; (void)n_in; (void)out_size; (void)ws_size;
  const float* mix   = (const float*)d_in[0];
  const float* spin  = (const float*)d_in[1];
  const float* doa   = (const float*)d_in[2];
  const float* enc_w = (const float*)d_in[3];
  const float* enc_b = (const float*)d_in[4];
  const float* enc_a = (const float*)d_in[5];
  const float* dqg_w = (const float*)d_in[6];
  const float* dqg_b = (const float*)d_in[7];
  const float* dec_w = (const float*)d_in[8];
  const float* dec_b = (const float*)d_in[9];
  const float* dec_a = (const float*)d_in[10];
  const float* qw    = (const float*)d_in[11];
  const float* qb    = (const float*)d_in[12];
  const float* kw    = (const float*)d_in[13];
  const float* kb    = (const float*)d_in[14];
  const float* vw    = (const float*)d_in[15];
  const float* vb    = (const float*)d_in[16];
  const float* oww   = (const float*)d_in[17];
  const float* obb   = (const float*)d_in[18];
  float* outp = (float*)d_out;

  unsigned short* w16 = (unsigned short*)d_ws;
  unsigned short* enc16 = w16;                 // 31*6144
  unsigned short* dec16 = w16 + 190464;        // 31*9216
  unsigned short* q16   = w16 + 476160;
  unsigned short* k16   = q16 + 9216;
  unsigned short* v16   = k16 + 9216;
  unsigned short* o16   = v16 + 9216;
  float* gbws = (float*)((char*)d_ws + 1026048);  // 31*4*192 f32

  hipLaunchKernelGGL(prep_w, dim3(512), dim3(256), 0, stream,
                     enc_w, dec_w, qw, kw, vw, oww, w16);
  hipLaunchKernelGGL(qp_kernel, dim3(NBANDS, 4), dim3(192), 0, stream,
                     doa, dqg_w, dqg_b, gbws);
  hipLaunchKernelGGL(fused_mfma, dim3(16448), dim3(256), 0, stream,
                     mix, spin, enc16, enc_b, enc_a, dec16, dec_b, dec_a, gbws,
                     q16, qb, k16, kb, v16, vb, o16, obb, outp);
}

// Round 7
// 578.874 us; speedup vs baseline: 1.5054x; 1.5054x over previous
//
#include <hip/hip_runtime.h>
#include <math.h>

#define NBANDS 31
#define FT 257000

typedef __attribute__((ext_vector_type(8))) short bh8;
typedef __attribute__((ext_vector_type(4))) float f4;

__constant__ int d_bs[NBANDS] = {0,1,1,2,2,2,3,3,4,5,6,7,8,10,11,13,16,19,23,27,32,38,45,54,64,76,91,108,128,152,181};
__constant__ int d_be[NBANDS] = {2,3,3,3,4,4,5,6,7,8,9,11,12,14,17,20,24,28,33,39,46,55,65,77,92,109,129,153,182,216,257};

__device__ __forceinline__ unsigned short b16u(float v) {
  __bf16 h = (__bf16)v;
  return __builtin_bit_cast(unsigned short, h);
}
__device__ __forceinline__ unsigned pk2(float a, float b) {
  return (unsigned)b16u(a) | ((unsigned)b16u(b) << 16);
}
__device__ __forceinline__ float hann1(int i, int L) {
  return 0.5f - 0.5f * cosf(6.283185307179586f * (float)i / (float)L);
}

// ---- weight f32 -> bf16 prep, permuted into MFMA-fragment order ----
__global__ __launch_bounds__(256) void prep_w(
    const float* __restrict__ enc_w, const float* __restrict__ dec_w,
    const float* __restrict__ qw, const float* __restrict__ kw,
    const float* __restrict__ vw, const float* __restrict__ ow,
    unsigned short* __restrict__ w16) {
  const int stride = gridDim.x * blockDim.x;
  for (int i = blockIdx.x * blockDim.x + threadIdx.x; i < 513024; i += stride) {
    float v;
    if (i < 190464) {                      // enc: K=64, KT=2
      const int k = i / 6144, r = i - k * 6144;
      const int tile = r >> 9, li = r & 511;
      const int lane = li >> 3, j = li & 7;
      const int g = lane >> 4, n = lane & 15;
      const int mt = tile >> 1, kt = tile & 1;
      v = enc_w[k * 6144 + (mt * 16 + n) * 64 + kt * 32 + g * 8 + j];
    } else if (i < 476160) {               // dec: K=96, KT=3
      const int i2 = i - 190464;
      const int k = i2 / 9216, r = i2 - k * 9216;
      const int tile = r >> 9, li = r & 511;
      const int lane = li >> 3, j = li & 7;
      const int g = lane >> 4, n = lane & 15;
      const int mt = tile / 3, kt = tile - mt * 3;
      v = dec_w[k * 9216 + (mt * 16 + n) * 96 + kt * 32 + g * 8 + j];
    } else {                               // q,k,v,o
      const int i2 = i - 476160;
      const int a = i2 / 9216, r = i2 - a * 9216;
      const int tile = r >> 9, li = r & 511;
      const int lane = li >> 3, j = li & 7;
      const int g = lane >> 4, n = lane & 15;
      const int mt = tile / 3, kt = tile - mt * 3;
      const float* src = (a == 0) ? qw : (a == 1) ? kw : (a == 2) ? vw : ow;
      v = src[(mt * 16 + n) * 96 + kt * 32 + g * 8 + j];
    }
    w16[i] = b16u(v);
  }
}

__global__ __launch_bounds__(192) void qp_kernel(const float* __restrict__ doa,
                                                 const float* __restrict__ dqg_w,
                                                 const float* __restrict__ dqg_b,
                                                 float* __restrict__ gbuf) {
  const int k = blockIdx.x, b = blockIdx.y;
  const int tid = threadIdx.x;
  __shared__ float sdoa[36];
  if (tid < 36) sdoa[tid] = doa[b * 36 + tid];
  __syncthreads();
  const float* wr = dqg_w + (k * 192 + tid) * 36;
  float acc = dqg_b[k * 192 + tid];
  #pragma unroll
  for (int i = 0; i < 36; ++i) acc = fmaf(wr[i], sdoa[i], acc);
  if (tid < 96) acc += 1.0f;
  gbuf[(k * 4 + b) * 192 + tid] = acc;
}

#define LDSWAIT asm volatile("s_waitcnt lgkmcnt(0)" ::: "memory")

__device__ __forceinline__ void init6(f4* acc, const float* s, int off) {
  #pragma unroll
  for (int mt = 0; mt < 6; ++mt) {
    const float4 bb = *reinterpret_cast<const float4*>(s + mt * 16 + off);
    acc[mt] = (f4){bb.x, bb.y, bb.z, bb.w};
  }
}
__device__ __forceinline__ void ln96(const f4* acc, float& mean, float& rs) {
  float sm = 0.f, sq = 0.f;
  #pragma unroll
  for (int mt = 0; mt < 6; ++mt)
    #pragma unroll
    for (int r = 0; r < 4; ++r) { const float v = acc[mt][r]; sm += v; sq = fmaf(v, v, sq); }
  sm += __shfl_xor(sm, 16); sm += __shfl_xor(sm, 32);
  sq += __shfl_xor(sq, 16); sq += __shfl_xor(sq, 32);
  mean = sm * (1.f / 96.f);
  rs = rsqrtf(sq * (1.f / 96.f) - mean * mean + 1e-5f);
}

// ---- fused MFMA kernel; R5 structure + LDS-staged params + dec-g0 prefetch ----
__global__ __launch_bounds__(256, 3) void fused_mfma(
    const float* __restrict__ mix, const float* __restrict__ spin,
    const unsigned short* __restrict__ enc16, const float* __restrict__ enc_b, const float* __restrict__ enc_a,
    const unsigned short* __restrict__ dec16, const float* __restrict__ dec_b, const float* __restrict__ dec_a,
    const float* __restrict__ gb,
    const unsigned short* __restrict__ q16, const float* __restrict__ qb,
    const unsigned short* __restrict__ k16, const float* __restrict__ kb,
    const unsigned short* __restrict__ v16, const float* __restrict__ vb,
    const unsigned short* __restrict__ o16, const float* __restrict__ ob,
    float* __restrict__ out) {
  const int id0 = (int)blockIdx.x;
  const int id  = (id0 & 7) * 2056 + (id0 >> 3);   // bijective XCD swizzle (16448 = 8*2056)
  const int tt  = id & 15;
  const int fb  = id >> 4;
  const int f   = fb % 257;
  const int b   = fb / 257;
  const int t0  = tt << 6;

  const int tid  = threadIdx.x;
  const int lane = tid & 63;
  const int w    = tid >> 6;
  const int g    = lane >> 4;
  const int n    = lane & 15;
  const int col  = (w << 4) + n;
  const int t    = t0 + col;
  const bool tv  = t < 1000;
  const int tcl  = tv ? t : 999;
  const int sw   = (n & 7) << 3;
  const int lb   = lane << 3;

  __shared__ __align__(16) unsigned short XT[64 * 128];
  __shared__ __align__(16) float stage[5 * 388 + 384]; // per band: encB96|decB96|gb192|ea,da,pad2
  unsigned short* xw = XT + col * 128;

  // contiguous band range covering f
  int k0 = 0; while (d_be[k0] <= f) ++k0;
  int k1 = k0; while (k1 < NBANDS && d_bs[k1] <= f) ++k1;
  const int nb = k1 - k0;

  // cooperative stage of biases + FiLM params + alphas + QKVO biases
  {
    const int tot = nb * 388 + 384;
    for (int i = tid; i < tot; i += 256) {
      const int kk = i / 388, r = i - kk * 388;
      float v = 0.f;
      if (kk < nb) {
        const int k = k0 + kk;
        v = (r < 96)  ? enc_b[k * 96 + r]
          : (r < 192) ? dec_b[k * 96 + (r - 96)]
          : (r < 384) ? gb[(k * 4 + b) * 192 + (r - 192)]
          : (r == 384) ? enc_a[k] : (r == 385) ? dec_a[k] : 0.f;
      } else {
        const int r2 = i - nb * 388;
        v = (r2 < 96) ? qb[r2] : (r2 < 192) ? kb[r2 - 96] : (r2 < 288) ? vb[r2 - 192] : ob[r2 - 288];
      }
      stage[i] = v;
    }
  }

  float wsum = 0.f;
  for (int k = k0; k < k1; ++k) wsum += hann1(f - d_bs[k], d_be[k] - d_bs[k]);
  const float winv = 1.0f / fmaxf(wsum, 1e-8f);

  const float* spL = spin + b * 64 * FT + f * 1000 + tcl;
  const float* mxL = mix  + b * 96 * FT + f * 1000 + tcl;

  // spin prefetch (read-once)
  bh8 spb[2];
  {
    float spf[16];
    #pragma unroll
    for (int j = 0; j < 8; ++j) spf[j]     = __builtin_nontemporal_load(spL + (g * 8 + j) * FT);
    #pragma unroll
    for (int j = 0; j < 8; ++j) spf[8 + j] = __builtin_nontemporal_load(spL + (32 + g * 8 + j) * FT);
    #pragma unroll
    for (int kt = 0; kt < 2; ++kt)
      #pragma unroll
      for (int j = 0; j < 8; ++j) spb[kt][j] = (short)b16u(spf[kt * 8 + j]);
  }

  __syncthreads();   // stage visible

  f4 macc[6];
  #pragma unroll
  for (int mt = 0; mt < 6; ++mt) macc[mt] = (f4){0.f, 0.f, 0.f, 0.f};

  const int oo = g * 4;

  // ---------------- band loop ----------------
  for (int k = k0; k < k1; ++k) {
    const unsigned short* ew  = enc16 + k * 6144 + lb;
    const unsigned short* dwp = dec16 + k * 9216 + lb;
    const float* stg = stage + (k - k0) * 388;

    // ---- enc: 96x64 ----
    f4 acc[6];
    init6(acc, stg, oo);
    #pragma unroll
    for (int kt = 0; kt < 2; ++kt)
      #pragma unroll
      for (int mt = 0; mt < 6; ++mt) {
        const bh8 af = *reinterpret_cast<const bh8*>(ew + ((mt * 2 + kt) << 9));
        acc[mt] = __builtin_amdgcn_mfma_f32_16x16x32_bf16(af, spb[kt], acc[mt], 0, 0, 0);
      }

    // prefetch dec g0 BEFORE the barrier: latency hides under LN/FiLM
    bh8 dpre[6];
    #pragma unroll
    for (int mt = 0; mt < 6; ++mt)
      dpre[mt] = *reinterpret_cast<const bh8*>(dwp + ((mt * 3) << 9));

    float mean, rs;
    ln96(acc, mean, rs);
    const float ea = stg[384];
    #pragma unroll
    for (int mt = 0; mt < 6; ++mt) {
      const float4 ga = *reinterpret_cast<const float4*>(stg + 192 + mt * 16 + oo);
      const float4 be = *reinterpret_cast<const float4*>(stg + 288 + mt * 16 + oo);
      float x0 = (acc[mt][0] - mean) * rs; x0 = (x0 >= 0.f) ? x0 : ea * x0;
      float x1 = (acc[mt][1] - mean) * rs; x1 = (x1 >= 0.f) ? x1 : ea * x1;
      float x2 = (acc[mt][2] - mean) * rs; x2 = (x2 >= 0.f) ? x2 : ea * x2;
      float x3 = (acc[mt][3] - mean) * rs; x3 = (x3 >= 0.f) ? x3 : ea * x3;
      uint2 u;
      u.x = pk2(fmaf(ga.x, x0, be.x), fmaf(ga.y, x1, be.y));
      u.y = pk2(fmaf(ga.z, x2, be.z), fmaf(ga.w, x3, be.w));
      *reinterpret_cast<uint2*>(xw + ((mt * 16 + g * 4) ^ sw)) = u;
    }
    LDSWAIT;

    // ---- dec: 96x96 from XT (g0 prefetched) ----
    f4 dacc[6];
    init6(dacc, stg + 96, oo);
    {
      const bh8 bf0 = *reinterpret_cast<const bh8*>(xw + ((0 * 32 + g * 8) ^ sw));
      #pragma unroll
      for (int mt = 0; mt < 6; ++mt)
        dacc[mt] = __builtin_amdgcn_mfma_f32_16x16x32_bf16(dpre[mt], bf0, dacc[mt], 0, 0, 0);
    }
    #pragma unroll
    for (int kt = 1; kt < 3; ++kt) {
      const bh8 bf = *reinterpret_cast<const bh8*>(xw + ((kt * 32 + g * 8) ^ sw));
      #pragma unroll
      for (int mt = 0; mt < 6; ++mt) {
        const bh8 af = *reinterpret_cast<const bh8*>(dwp + ((mt * 3 + kt) << 9));
        dacc[mt] = __builtin_amdgcn_mfma_f32_16x16x32_bf16(af, bf, dacc[mt], 0, 0, 0);
      }
    }
    float mean2, rs2;
    ln96(dacc, mean2, rs2);
    const float da = stg[385];
    const float win = hann1(f - d_bs[k], d_be[k] - d_bs[k]);
    #pragma unroll
    for (int mt = 0; mt < 6; ++mt)
      #pragma unroll
      for (int r = 0; r < 4; ++r) {
        float x = (dacc[mt][r] - mean2) * rs2;
        x = (x >= 0.f) ? x : da * x;
        macc[mt][r] = fmaf(win, x, macc[mt][r]);
      }
  }

  // ---- mix loads (cached; residual re-read hits L2) ----
  float mxf[24];
  #pragma unroll
  for (int kt = 0; kt < 3; ++kt)
    #pragma unroll
    for (int j = 0; j < 8; ++j) mxf[kt * 8 + j] = mxL[(kt * 32 + g * 8 + j) * FT];

  // ---- merged -> XT ----
  #pragma unroll
  for (int mt = 0; mt < 6; ++mt) {
    uint2 u;
    u.x = pk2(macc[mt][0] * winv, macc[mt][1] * winv);
    u.y = pk2(macc[mt][2] * winv, macc[mt][3] * winv);
    *reinterpret_cast<uint2*>(xw + ((mt * 16 + g * 4) ^ sw)) = u;
  }
  LDSWAIT;
  bh8 gfr[3];
  #pragma unroll
  for (int kt = 0; kt < 3; ++kt) gfr[kt] = *reinterpret_cast<const bh8*>(xw + ((kt * 32 + g * 8) ^ sw));

  bh8 mxb[3];
  #pragma unroll
  for (int kt = 0; kt < 3; ++kt)
    #pragma unroll
    for (int j = 0; j < 8; ++j) mxb[kt][j] = (short)b16u(mxf[kt * 8 + j]);

  const float* stQ = stage + nb * 388;

  // ---- Q (mix), K (merged) ----
  f4 qacc[6];
  init6(qacc, stQ, oo);
  const unsigned short* qp16 = q16 + lb;
  #pragma unroll
  for (int kt = 0; kt < 3; ++kt)
    #pragma unroll
    for (int mt = 0; mt < 6; ++mt) {
      const bh8 af = *reinterpret_cast<const bh8*>(qp16 + ((mt * 3 + kt) << 9));
      qacc[mt] = __builtin_amdgcn_mfma_f32_16x16x32_bf16(af, mxb[kt], qacc[mt], 0, 0, 0);
    }
  f4 kacc[6];
  init6(kacc, stQ + 96, oo);
  const unsigned short* kp16 = k16 + lb;
  #pragma unroll
  for (int kt = 0; kt < 3; ++kt)
    #pragma unroll
    for (int mt = 0; mt < 6; ++mt) {
      const bh8 af = *reinterpret_cast<const bh8*>(kp16 + ((mt * 3 + kt) << 9));
      kacc[mt] = __builtin_amdgcn_mfma_f32_16x16x32_bf16(af, gfr[kt], kacc[mt], 0, 0, 0);
    }
  float p = 0.f;
  #pragma unroll
  for (int mt = 0; mt < 6; ++mt)
    #pragma unroll
    for (int r = 0; r < 4; ++r) p = fmaf(qacc[mt][r], kacc[mt][r], p);
  p += __shfl_xor(p, 16); p += __shfl_xor(p, 32);
  const float sig = 1.f / (1.f + __expf(-p * 0.10206207261596575f));

  // ---- V, attended -> XT ----
  f4 vacc[6];
  init6(vacc, stQ + 192, oo);
  const unsigned short* vp16 = v16 + lb;
  #pragma unroll
  for (int kt = 0; kt < 3; ++kt)
    #pragma unroll
    for (int mt = 0; mt < 6; ++mt) {
      const bh8 af = *reinterpret_cast<const bh8*>(vp16 + ((mt * 3 + kt) << 9));
      vacc[mt] = __builtin_amdgcn_mfma_f32_16x16x32_bf16(af, gfr[kt], vacc[mt], 0, 0, 0);
    }
  #pragma unroll
  for (int mt = 0; mt < 6; ++mt) {
    uint2 u;
    u.x = pk2(vacc[mt][0] * sig, vacc[mt][1] * sig);
    u.y = pk2(vacc[mt][2] * sig, vacc[mt][3] * sig);
    *reinterpret_cast<uint2*>(xw + ((mt * 16 + g * 4) ^ sw)) = u;
  }
  // residual loads issue before the wait, consumed at store
  float mres[6][4];
  #pragma unroll
  for (int mt = 0; mt < 6; ++mt)
    #pragma unroll
    for (int r = 0; r < 4; ++r) mres[mt][r] = mxL[(mt * 16 + g * 4 + r) * FT];
  LDSWAIT;
  bh8 afr[3];
  #pragma unroll
  for (int kt = 0; kt < 3; ++kt) afr[kt] = *reinterpret_cast<const bh8*>(xw + ((kt * 32 + g * 8) ^ sw));

  f4 oacc[6];
  init6(oacc, stQ + 288, oo);
  const unsigned short* op16 = o16 + lb;
  #pragma unroll
  for (int kt = 0; kt < 3; ++kt)
    #pragma unroll
    for (int mt = 0; mt < 6; ++mt) {
      const bh8 af = *reinterpret_cast<const bh8*>(op16 + ((mt * 3 + kt) << 9));
      oacc[mt] = __builtin_amdgcn_mfma_f32_16x16x32_bf16(af, afr[kt], oacc[mt], 0, 0, 0);
    }

  if (tv) {
    #pragma unroll
    for (int mt = 0; mt < 6; ++mt) {
      const int base = (b * 96 + mt * 16 + g * 4) * FT + f * 1000 + t;
      #pragma unroll
      for (int r = 0; r < 4; ++r)
        __builtin_nontemporal_store(mres[mt][r] + oacc[mt][r], out + base + r * FT);
    }
  }
}

extern "C" void kernel_launch(void* const* d_in, const int* in_sizes, int n_in,
                              void* d_out, int out_size, void* d_ws, size_t ws_size,
                              hipStream_t stream) {
  (void)in_sizes; (void)n_in; (void)out_size; (void)ws_size;
  const float* mix   = (const float*)d_in[0];
  const float* spin  = (const float*)d_in[1];
  const float* doa   = (const float*)d_in[2];
  const float* enc_w = (const float*)d_in[3];
  const float* enc_b = (const float*)d_in[4];
  const float* enc_a = (const float*)d_in[5];
  const float* dqg_w = (const float*)d_in[6];
  const float* dqg_b = (const float*)d_in[7];
  const float* dec_w = (const float*)d_in[8];
  const float* dec_b = (const float*)d_in[9];
  const float* dec_a = (const float*)d_in[10];
  const float* qw    = (const float*)d_in[11];
  const float* qb    = (const float*)d_in[12];
  const float* kw    = (const float*)d_in[13];
  const float* kb    = (const float*)d_in[14];
  const float* vw    = (const float*)d_in[15];
  const float* vb    = (const float*)d_in[16];
  const float* oww   = (const float*)d_in[17];
  const float* obb   = (const float*)d_in[18];
  float* outp = (float*)d_out;

  unsigned short* w16 = (unsigned short*)d_ws;
  unsigned short* enc16 = w16;                 // 31*6144
  unsigned short* dec16 = w16 + 190464;        // 31*9216
  unsigned short* q16   = w16 + 476160;
  unsigned short* k16   = q16 + 9216;
  unsigned short* v16   = k16 + 9216;
  unsigned short* o16   = v16 + 9216;
  float* gbws = (float*)((char*)d_ws + 1026048);  // 31*4*192 f32

  hipLaunchKernelGGL(prep_w, dim3(512), dim3(256), 0, stream,
                     enc_w, dec_w, qw, kw, vw, oww, w16);
  hipLaunchKernelGGL(qp_kernel, dim3(NBANDS, 4), dim3(192), 0, stream,
                     doa, dqg_w, dqg_b, gbws);
  hipLaunchKernelGGL(fused_mfma, dim3(16448), dim3(256), 0, stream,
                     mix, spin, enc16, enc_b, enc_a, dec16, dec_b, dec_a, gbws,
                     q16, qb, k16, kb, v16, vb, o16, obb, outp);
}